// Round 4
// baseline (325.947 us; speedup 1.0000x reference)
//
#include <hip/hip_runtime.h>
#include <stdint.h>

#define NEGV -10000000.0f

typedef __attribute__((ext_vector_type(8))) short short8;
typedef __attribute__((ext_vector_type(4))) float f32x4;

__device__ __forceinline__ ushort f2b(float f) {
    uint32_t x = __float_as_uint(f);
    uint32_t r = x + 0x7FFFu + ((x >> 16) & 1u);
    return (ushort)(r >> 16);
}
__device__ __forceinline__ float b2f(ushort u) {
    union { float f; uint32_t i; } v; v.i = ((uint32_t)u) << 16; return v.f;
}

// ---------------- Kernel 0: per-n prep ------------------------------------------
// Bhat[n][j][d<224] = bf16(U*w_hu + w_h) (zero-padded), c[n][j] = dot(U[j],w_u)+b,
// UT[n][d<224][j]   = bf16(U^T) (B-fragment layout for GEMM2).
__launch_bounds__(256)
__global__ void k0_prep(const float* __restrict__ Ug, const float* __restrict__ wg,
                        const float* __restrict__ bg,
                        ushort* __restrict__ BhatW, ushort* __restrict__ UTW,
                        float* __restrict__ cW) {
    __shared__ __align__(16) float sU[64][204];   // pad 204: col-read 8-way not 16-way
    __shared__ float sW[600];
    const int tid = threadIdx.x, lane = tid & 63, wid = tid >> 6;
    const int n = blockIdx.x;

    for (int i = tid; i < 600; i += 256) sW[i] = wg[i];
    for (int r = wid; r < 64; r += 4) {
        const float* urow = Ug + (size_t)(n * 64 + r) * 200;
        if (lane < 50) *(float4*)&sU[r][lane * 4] = *(const float4*)(urow + lane * 4);
    }
    __syncthreads();
    const float bval = bg[0];

    ushort* utn = UTW + (size_t)n * 224 * 64;
    for (int d = wid; d < 224; d += 4)
        utn[d * 64 + lane] = (d < 200) ? f2b(sU[lane][d]) : (ushort)0;

    ushort* bhn = BhatW + (size_t)n * 64 * 224;
    for (int r = wid; r < 64; r += 4) {
        float part = 0.f;
        for (int d = lane; d < 224; d += 64) {
            float bh = 0.f;
            if (d < 200) {
                float u = sU[r][d];
                bh = u * sW[400 + d] + sW[d];
                part += u * sW[200 + d];
            }
            bhn[r * 224 + d] = f2b(bh);
        }
        #pragma unroll
        for (int off = 32; off >= 1; off >>= 1) part += __shfl_xor(part, off);
        if (lane == 0) cW[n * 64 + r] = part + bval;
    }
}

// ---------------- Kernel 13: fused GEMM1 + J-softmax + GEMM2 + G[0:600] ----------
// ONE WAVE per block, 16 t-rows, grid (64, 64) = 4096 blocks (~12/CU resident).
// No __syncthreads anywhere (wave-private LDS). P stays on-chip.
__launch_bounds__(64)
__global__ void k13_fused(const float* __restrict__ Hg,
                          const ushort* __restrict__ BhatW,
                          const float* __restrict__ cW,
                          const float* __restrict__ qmg,
                          const ushort* __restrict__ UTW,
                          float* __restrict__ SmaxWs,
                          float* __restrict__ Gout) {
    __shared__ ushort sP[16][76];    // P tile (bf16), padded
    __shared__ ushort sU2[16][204];  // U_ tile (bf16), row-stride 408B (8B-aligned)
    const int lane = threadIdx.x;
    const int g = lane >> 4, li = lane & 15;
    const int n = blockIdx.y, t0 = blockIdx.x * 16;

    const float*  Hrow = Hg + (size_t)(n * 1024 + t0 + li) * 200;
    const ushort* Bn   = BhatW + (size_t)n * 64 * 224;

    // ---- GEMM1: prefetch all A-fragments (H, bf16-converted), then MFMA ----
    short8 av[7];
    #pragma unroll
    for (int kc = 0; kc < 7; ++kc) {
        if (kc < 6 || g == 0) {   // kc==6,g>0 would read past d=200
            float4 h0 = *(const float4*)(Hrow + kc * 32 + g * 8);
            float4 h1 = *(const float4*)(Hrow + kc * 32 + g * 8 + 4);
            av[kc][0] = (short)f2b(h0.x); av[kc][1] = (short)f2b(h0.y);
            av[kc][2] = (short)f2b(h0.z); av[kc][3] = (short)f2b(h0.w);
            av[kc][4] = (short)f2b(h1.x); av[kc][5] = (short)f2b(h1.y);
            av[kc][6] = (short)f2b(h1.z); av[kc][7] = (short)f2b(h1.w);
        } else {
            av[kc] = (short8){0, 0, 0, 0, 0, 0, 0, 0};
        }
    }
    f32x4 acc[4];
    #pragma unroll
    for (int jt = 0; jt < 4; ++jt) acc[jt] = (f32x4){0.f, 0.f, 0.f, 0.f};
    #pragma unroll
    for (int kc = 0; kc < 7; ++kc) {
        #pragma unroll
        for (int jt = 0; jt < 4; ++jt) {
            short8 bv = *(const short8*)(Bn + (size_t)(jt * 16 + li) * 224 + kc * 32 + g * 8);
            acc[jt] = __builtin_amdgcn_mfma_f32_16x16x32_bf16(av[kc], bv, acc[jt], 0, 0, 0);
        }
    }

    // ---- J-softmax (identical math to verified k1) ----
    float cj[4], qm[4];
    #pragma unroll
    for (int jt = 0; jt < 4; ++jt) {
        cj[jt] = cW[n * 64 + jt * 16 + li];
        qm[jt] = qmg[n * 64 + jt * 16 + li];
    }
    #pragma unroll
    for (int reg = 0; reg < 4; ++reg) {
        float x[4], y[4];
        float xm = -1e30f, ym = -1e30f;
        #pragma unroll
        for (int jt = 0; jt < 4; ++jt) {
            float s = acc[jt][reg] + cj[jt];
            x[jt] = s * qm[jt];
            y[jt] = (qm[jt] != 0.f) ? s : NEGV;
            xm = fmaxf(xm, x[jt]); ym = fmaxf(ym, y[jt]);
        }
        #pragma unroll
        for (int off = 1; off <= 8; off <<= 1) {
            xm = fmaxf(xm, __shfl_xor(xm, off));
            ym = fmaxf(ym, __shfl_xor(ym, off));
        }
        float e[4], z = 0.f, zm = 0.f;
        #pragma unroll
        for (int jt = 0; jt < 4; ++jt) {
            e[jt] = __expf(x[jt] - xm);
            z += e[jt]; zm += e[jt] * qm[jt];
        }
        #pragma unroll
        for (int off = 1; off <= 8; off <<= 1) {
            z  += __shfl_xor(z, off);
            zm += __shfl_xor(zm, off);
        }
        float inv = 1.f / (zm + 1e-13f * z);
        int trow = g * 4 + reg;
        #pragma unroll
        for (int jt = 0; jt < 4; ++jt) sP[trow][jt * 16 + li] = f2b(e[jt] * qm[jt] * inv);
        if (li == 0) SmaxWs[n * 1024 + t0 + trow] = ym;
    }

    // ---- GEMM2: U_ = P @ U (A from sP, B from precomputed U^T) ----
    const ushort* UTn = UTW + (size_t)n * 224 * 64;
    f32x4 acc2[13];
    #pragma unroll
    for (int dt = 0; dt < 13; ++dt) acc2[dt] = (f32x4){0.f, 0.f, 0.f, 0.f};
    #pragma unroll
    for (int kc = 0; kc < 2; ++kc) {
        short8 a2 = *(const short8*)(&sP[li][kc * 32 + g * 8]);
        #pragma unroll
        for (int dt = 0; dt < 13; ++dt) {
            short8 bv = *(const short8*)(UTn + (size_t)(dt * 16 + li) * 64 + kc * 32 + g * 8);
            acc2[dt] = __builtin_amdgcn_mfma_f32_16x16x32_bf16(a2, bv, acc2[dt], 0, 0, 0);
        }
    }

    // ---- stage U_ (bf16, same precision as verified R0 kernel) ----
    #pragma unroll
    for (int dt = 0; dt < 13; ++dt) {
        int d = dt * 16 + li;
        if (d < 200) {
            #pragma unroll
            for (int reg = 0; reg < 4; ++reg)
                sU2[g * 4 + reg][d] = f2b(acc2[dt][reg]);
        }
    }

    // ---- epilogue: G[:, 0:600] = [H | U_ | H*U_], coalesced 800B segments ----
    for (int r = 0; r < 16; ++r) {
        if (lane < 50) {
            int d0 = lane * 4;
            const float* hrow = Hg + (size_t)(n * 1024 + t0 + r) * 200;
            float* orow = Gout + (size_t)(n * 1024 + t0 + r) * 800;
            f32x4 h = *(const f32x4*)(hrow + d0);
            uint2 uraw = *(const uint2*)&sU2[r][d0];
            f32x4 u;
            u[0] = b2f((ushort)(uraw.x & 0xffffu)); u[1] = b2f((ushort)(uraw.x >> 16));
            u[2] = b2f((ushort)(uraw.y & 0xffffu)); u[3] = b2f((ushort)(uraw.y >> 16));
            f32x4 hu = h * u;
            __builtin_nontemporal_store(h,  (f32x4*)(orow + d0));
            __builtin_nontemporal_store(u,  (f32x4*)(orow + 200 + d0));
            __builtin_nontemporal_store(hu, (f32x4*)(orow + 400 + d0));
        }
    }
}

// ---------------- Kernel 2a: T-softmax stats -> a; zero Hbar ---------------------
__launch_bounds__(256)
__global__ void k2a_softmaxT(const float* __restrict__ cmg,
                             const float* __restrict__ SmaxWs,
                             float* __restrict__ aWs,
                             float* __restrict__ HbarWs) {
    __shared__ float red[8];
    const int tid = threadIdx.x, lane = tid & 63, wid = tid >> 6;
    const int n = blockIdx.x;

    float x[4], m[4];
    #pragma unroll
    for (int i = 0; i < 4; ++i) {
        int t = tid + 256 * i;
        float v = SmaxWs[n * 1024 + t];
        m[i] = cmg[(size_t)n * 1024 + t];
        x[i] = v * m[i];
    }
    float mx = fmaxf(fmaxf(x[0], x[1]), fmaxf(x[2], x[3]));
    #pragma unroll
    for (int off = 32; off >= 1; off >>= 1) mx = fmaxf(mx, __shfl_xor(mx, off));
    if (lane == 0) red[wid] = mx;
    __syncthreads();
    float M = fmaxf(fmaxf(red[0], red[1]), fmaxf(red[2], red[3]));
    __syncthreads();
    float e[4], z = 0.f, zm = 0.f;
    #pragma unroll
    for (int i = 0; i < 4; ++i) {
        e[i] = __expf(x[i] - M);
        z += e[i]; zm += e[i] * m[i];
    }
    #pragma unroll
    for (int off = 32; off >= 1; off >>= 1) {
        z  += __shfl_xor(z, off);
        zm += __shfl_xor(zm, off);
    }
    if (lane == 0) { red[wid] = z; red[4 + wid] = zm; }
    __syncthreads();
    float Z  = red[0] + red[1] + red[2] + red[3];
    float Zm = red[4] + red[5] + red[6] + red[7];
    float inv = 1.f / (Zm + 1e-13f * Z);
    #pragma unroll
    for (int i = 0; i < 4; ++i) aWs[n * 1024 + tid + 256 * i] = e[i] * m[i] * inv;
    if (tid < 200) HbarWs[n * 200 + tid] = 0.f;
}

// ---------------- Kernel 2b: Hbar += a-chunk @ H-chunk ---------------------------
__launch_bounds__(256)
__global__ void k2b_hbar(const float* __restrict__ Hg,
                         const float* __restrict__ aWs,
                         float* __restrict__ HbarWs) {
    __shared__ float sA[64];
    const int tid = threadIdx.x;
    const int n = blockIdx.y, t0 = blockIdx.x * 64;
    if (tid < 64) sA[tid] = aWs[n * 1024 + t0 + tid];
    __syncthreads();
    if (tid < 200) {
        const float* hp = Hg + (size_t)(n * 1024 + t0) * 200 + tid;
        float acc = 0.f;
        #pragma unroll 8
        for (int t = 0; t < 64; ++t) acc += sA[t] * hp[(size_t)t * 200];
        atomicAdd(HbarWs + n * 200 + tid, acc);
    }
}

// ---------------- Kernel 4: G[:, 600:800] = H * Hbar -----------------------------
__launch_bounds__(256)
__global__ void k4_hh(const float* __restrict__ Hg,
                      const float* __restrict__ HbarWs,
                      float* __restrict__ Gout) {
    __shared__ __align__(16) float sHb[200];
    const int tid = threadIdx.x, lane = tid & 63, wid = tid >> 6;
    const int n = blockIdx.y, t0 = blockIdx.x * 64;
    if (tid < 200) sHb[tid] = HbarWs[n * 200 + tid];
    __syncthreads();
    for (int r = wid; r < 64; r += 4) {
        if (lane < 50) {
            int d0 = lane * 4;
            const float* hrow = Hg + (size_t)(n * 1024 + t0 + r) * 200;
            float* orow = Gout + (size_t)(n * 1024 + t0 + r) * 800;
            f32x4 h  = *(const f32x4*)(hrow + d0);
            f32x4 hb = *(const f32x4*)&sHb[d0];
            f32x4 hh = h * hb;
            __builtin_nontemporal_store(hh, (f32x4*)(orow + 600 + d0));
        }
    }
}

extern "C" void kernel_launch(void* const* d_in, const int* in_sizes, int n_in,
                              void* d_out, int out_size, void* d_ws, size_t ws_size,
                              hipStream_t stream) {
    (void)in_sizes; (void)n_in; (void)out_size; (void)ws_size;
    const float* Hg  = (const float*)d_in[0];
    const float* Ug  = (const float*)d_in[1];
    const float* cmg = (const float*)d_in[2];
    const float* qmg = (const float*)d_in[3];
    const float* wg  = (const float*)d_in[4];
    const float* bg  = (const float*)d_in[5];
    float* Gout = (float*)d_out;

    char* ws = (char*)d_ws;
    float*  SmaxWs = (float*) (ws);                    // 64*1024*4   =   262,144
    float*  aWs    = (float*) (ws + 262144);           // 64*1024*4   =   262,144
    float*  HbarWs = (float*) (ws + 524288);           // 64*200*4    =    51,200
    float*  cWs    = (float*) (ws + 575488);           // 64*64*4     =    16,384
    ushort* BhatWs = (ushort*)(ws + 591872);           // 64*64*224*2 = 1,835,008
    ushort* UTWs   = (ushort*)(ws + 2426880);          // 64*224*64*2 = 1,835,008
                                                       // total       = 4,261,888

    dim3 blk256(256, 1, 1);
    k0_prep<<<dim3(64, 1, 1), blk256, 0, stream>>>(Ug, wg, bg, BhatWs, UTWs, cWs);
    k13_fused<<<dim3(64, 64, 1), dim3(64, 1, 1), 0, stream>>>(Hg, BhatWs, cWs, qmg,
                                                              UTWs, SmaxWs, Gout);
    k2a_softmaxT<<<dim3(64, 1, 1), blk256, 0, stream>>>(cmg, SmaxWs, aWs, HbarWs);
    k2b_hbar<<<dim3(16, 64, 1), blk256, 0, stream>>>(Hg, aWs, HbarWs);
    k4_hh<<<dim3(16, 64, 1), blk256, 0, stream>>>(Hg, HbarWs, Gout);
}